// Round 3
// baseline (214.318 us; speedup 1.0000x reference)
//
#include <hip/hip_runtime.h>
#include <stdint.h>

// KANLinear fused kernel v3 for MI355X (gfx950).
// out = x @ bw + scaling * einsum('bik,iok->bo', basis(x), sw)
// One bf16 MFMA GEMM: K = 256 i-slabs x 80 (66 basis + base term at k=66 + zero pad).
// v3 changes vs v2 (MfmaUtil 21.6%, VALUBusy 46%; basis VALU + divergence bound):
//   - wave-specialized basis: waves 0-3 compute the two aligned 16-slot window chunks
//     (32 exps per (row,slab), natural zeros outside; exact to ~1e-13), waves 4-7 write
//     the 3 complementary zero chunks + x at slot 66. Wave-uniform branch, no divergence.
//   - wave tile 128x32 (was 64x64): each B element loaded once per block -> B-from-L2
//     per CU/slab halves (1460 -> 730 cyc), hidden under the 1280-cyc MFMA wall.
//   - kan_pack rewritten with LDS transpose: coalesced contiguous loads of sw.

#define IN_F 256
#define OUT_F 256
#define NB 66
#define KP 80        // padded K per i-slab: 66 basis + base at k=66 + zeros, = 5 x K16
#define APAD 88      // A LDS row stride in ushorts
#define KSPLIT 8
#define SLABS 32     // IN_F / KSPLIT
#define BM 128
#define NTHREADS 512

typedef __attribute__((ext_vector_type(8))) short bf16x8;
typedef __attribute__((ext_vector_type(16))) float f32x16;

__device__ __forceinline__ unsigned int f2bf(float f) {
  unsigned int u = __float_as_uint(f);
  u += 0x7FFFu + ((u >> 16) & 1u);   // round-to-nearest-even
  return u >> 16;
}

// ---- scaling partial: block b sums i in [b*32, b*32+32) ----
__global__ void kan_scale8(const float* __restrict__ sca, float* __restrict__ wsp) {
  const int o = threadIdx.x, b = blockIdx.x;
  float s = 0.0f;
  #pragma unroll
  for (int j = 0; j < 32; j++) {
    const int i = b * 32 + j;
    s += fmaxf(sca[(size_t)i * OUT_F + o], 1e-7f);
  }
  wsp[b * OUT_F + o] = s;
}

// ---- pack W' -> wp2, layout (i*10 + g)*256 + o as uint4 (8 bf16), g-chunk k = g*8+j ----
// k<66 = sw*scaling[o]; k=66 = bw; 67..79 = 0. LDS transpose for coalesced global reads.
__global__ void kan_pack(const float* __restrict__ sw, const float* __restrict__ bw,
                         const float* __restrict__ wsp, unsigned short* __restrict__ wp2) {
  __shared__ float S[128 * 68 + 64];
  __shared__ float sc[256];
  const int t = threadIdx.x, i = blockIdx.x;
  {
    float s = 0.0f;
    #pragma unroll
    for (int b = 0; b < 8; b++) s += wsp[b * OUT_F + t];
    sc[t] = s * (1.0f / 256.0f);
  }
  uint4* wp2u4 = (uint4*)wp2;
  for (int hf = 0; hf < 2; hf++) {
    __syncthreads();
    // coalesced load of half-slab (128 o's x 66 k = 8448 contiguous floats)
    const float* src = sw + ((size_t)i * 256 + hf * 128) * NB;
    #pragma unroll
    for (int r2 = 0; r2 < 33; r2++) {
      const int idx = r2 * 256 + t;
      const int o = idx / 66;
      const int k = idx - o * 66;
      S[o * 68 + k] = src[idx];
    }
    __syncthreads();
    const int ol = t >> 1, hh = t & 1;
    const int og = hf * 128 + ol;
    const float scv = sc[og];
    const float bwv = bw[(size_t)i * 256 + og];
    #pragma unroll
    for (int gg = 0; gg < 5; gg++) {
      const int g = hh * 5 + gg;
      const int kb = g * 8;
      unsigned int u[4];
      #pragma unroll
      for (int j = 0; j < 4; j++) {
        const int k0 = kb + 2 * j, k1 = k0 + 1;
        float f0 = S[ol * 68 + k0] * scv;   // in-bounds garbage if k0>=66, masked below
        float f1 = S[ol * 68 + k1] * scv;
        f0 = (k0 < 66) ? f0 : ((k0 == 66) ? bwv : 0.0f);
        f1 = (k1 < 66) ? f1 : ((k1 == 66) ? bwv : 0.0f);
        u[j] = f2bf(f0) | (f2bf(f1) << 16);
      }
      uint4 v; v.x = u[0]; v.y = u[1]; v.z = u[2]; v.w = u[3];
      wp2u4[((size_t)i * 10 + g) * 256 + og] = v;
    }
  }
}

// ---- main fused GEMM ----
__global__ __launch_bounds__(NTHREADS, 2) void kan_main(
    const float* __restrict__ x, const unsigned short* __restrict__ wp2,
    float* __restrict__ dst, int atomic_mode) {
  __shared__ unsigned short A[2][BM * APAD];   // 45056 B

  const int t = threadIdx.x;
  const int lane = t & 63;
  const int w = t >> 6;            // 0..7 -> wave col group (32 cols each)
  const int ml = lane & 31;
  const int half = lane >> 5;
  const int mblk = (int)blockIdx.x >> 3;
  const int kidx = (int)blockIdx.x & 7;   // XCD-affine split-K index (blk%8 -> XCD)
  const int b0 = mblk * BM;
  const int ibase = kidx * SLABS;

  // basis mapping: waves 0-3 (t<256) = window compute, waves 4-7 = const chunks
  const int rb = (t & 255) >> 1;   // row 0..127
  const int hh = t & 1;
  const bool heavy = (t < 256);    // wave-uniform

  const float* xrow = x + (size_t)(b0 + rb) * IN_F;
  // B frag for 32x32x16: col = w*32 + ml, k = half*8 + j; wp2 g = kk*2 + half
  const unsigned short* bbase = wp2 + (size_t)half * 2048 + (w * 32 + ml) * 8;

  bf16x8 breg[2][5];
  f32x16 acc[4] = {f32x16{}, f32x16{}, f32x16{}, f32x16{}};

#define LOADB(P, ISLAB)                                                        \
  {                                                                            \
    const unsigned short* bp = bbase + (size_t)(ISLAB) * (OUT_F * KP);         \
    _Pragma("unroll") for (int kk = 0; kk < 5; kk++)                           \
        breg[P][kk] = *(const bf16x8*)(bp + kk * 4096);                        \
  }

  // one basis stage: fill A[BUF] rows for slab value XV (per-thread row rb)
#define STAGE(BUF, XV)                                                         \
  {                                                                            \
    const float xr_ = (XV);                                                    \
    const float xc_ = fminf(fmaxf(xr_, -1.0f), 1.0f);                          \
    const float xs_ = (xc_ + 1.0f) * (63.0f / (2.0f + 1e-7f));                 \
    const float tl_ = xs_ - fminf(floorf(xs_), 61.0f);                         \
    const int kc_ = (int)(tl_ * 65.0f + 0.5f);                                 \
    const int c0_ = (min(max(kc_ - 8, 0), 50)) >> 4;                           \
    unsigned short* Ar = &A[BUF][rb * APAD];                                   \
    if (heavy) {                                                               \
      const int kb = (c0_ + hh) * 16;                                          \
      float vv[16];                                                            \
      float s_ = 0.0f;                                                         \
      _Pragma("unroll") for (int j = 0; j < 16; j++) {                         \
        const float d_ = tl_ - (float)(kb + j) * (1.0f / 65.0f);               \
        float ee = __expf(-2178.0f * d_ * d_);                                 \
        ee = (kb + j < 66) ? ee : 0.0f;                                        \
        vv[j] = ee;                                                            \
        s_ += ee;                                                              \
      }                                                                        \
      s_ += __shfl_xor(s_, 1);                                                 \
      const float r_ = __fdividef(1.0f, s_ + 1e-7f);                           \
      unsigned int u[8];                                                       \
      _Pragma("unroll") for (int j = 0; j < 8; j++) {                          \
        float f0 = vv[2 * j] * r_;                                             \
        float f1 = vv[2 * j + 1] * r_;                                         \
        f0 = (kb + 2 * j == 66) ? xr_ : f0;                                    \
        f1 = (kb + 2 * j + 1 == 66) ? xr_ : f1;                                \
        u[j] = f2bf(f0) | (f2bf(f1) << 16);                                    \
      }                                                                        \
      uint4 v0, v1;                                                            \
      v0.x = u[0]; v0.y = u[1]; v0.z = u[2]; v0.w = u[3];                      \
      v1.x = u[4]; v1.y = u[5]; v1.z = u[6]; v1.w = u[7];                      \
      *(uint4*)(Ar + kb) = v0;                                                 \
      *(uint4*)(Ar + kb + 8) = v1;                                             \
    } else {                                                                   \
      const int f0_ = (c0_ == 0) ? 2 : 0;                                      \
      const int f1_ = (c0_ <= 1) ? 3 : 1;                                      \
      const int f2_ = (c0_ == 3) ? 2 : 4;                                      \
      uint4 z; z.x = 0; z.y = 0; z.z = 0; z.w = 0;                             \
      if (hh == 0) {                                                           \
        *(uint4*)(Ar + f0_ * 16) = z;                                          \
        *(uint4*)(Ar + f0_ * 16 + 8) = z;                                      \
        *(uint4*)(Ar + f1_ * 16) = z;                                          \
        *(uint4*)(Ar + f1_ * 16 + 8) = z;                                      \
      } else {                                                                 \
        uint4 a = z;                                                           \
        a.y = (f2_ == 4) ? f2bf(xr_) : 0u;  /* slot 66 lives in chunk 4 dw1 */ \
        *(uint4*)(Ar + f2_ * 16) = a;                                          \
        *(uint4*)(Ar + f2_ * 16 + 8) = z;                                      \
      }                                                                        \
    }                                                                          \
  }

#define MFMA_SLAB(CUR, P)                                                      \
  {                                                                            \
    const unsigned short* Ac = &A[CUR][ml * APAD + half * 8];                  \
    _Pragma("unroll") for (int kk = 0; kk < 5; kk++) {                         \
      _Pragma("unroll") for (int mb = 0; mb < 4; mb++) {                       \
        bf16x8 af = *(const bf16x8*)(Ac + mb * 32 * APAD + kk * 16);           \
        acc[mb] = __builtin_amdgcn_mfma_f32_32x32x16_bf16(af, breg[P][kk],     \
                                                          acc[mb], 0, 0, 0);  \
      }                                                                        \
    }                                                                          \
  }

  // ---- prologue ----
  STAGE(0, xrow[ibase]);
  LOADB(0, ibase);
  float xn = xrow[ibase + 1];
  __syncthreads();

  for (int ii = 0; ii < SLABS; ii++) {
    const int cur = ii & 1;
    if (ii + 1 < SLABS) LOADB(1 - cur, ibase + ii + 1);
    MFMA_SLAB(cur, cur);
    const float xc2 = xn;
    if (ii + 2 < SLABS) xn = xrow[ibase + ii + 2];
    if (ii + 1 < SLABS) STAGE(1 - cur, xc2);
    __syncthreads();
  }

  // ---- epilogue: C/D layout col=lane&31, row=(r&3)+8*(r>>2)+4*(lane>>5) ----
  const int colb = w * 32 + ml;
  if (atomic_mode) {
    #pragma unroll
    for (int mb = 0; mb < 4; mb++) {
      #pragma unroll
      for (int r = 0; r < 16; r++) {
        const int row = b0 + mb * 32 + (r & 3) + 8 * (r >> 2) + 4 * half;
        atomicAdd(&dst[(size_t)row * OUT_F + colb], acc[mb][r]);
      }
    }
  } else {
    float* pd = dst + (size_t)kidx * ((size_t)4096 * OUT_F);
    #pragma unroll
    for (int mb = 0; mb < 4; mb++) {
      #pragma unroll
      for (int r = 0; r < 16; r++) {
        const int row = b0 + mb * 32 + (r & 3) + 8 * (r >> 2) + 4 * half;
        pd[(size_t)row * OUT_F + colb] = acc[mb][r];
      }
    }
  }
}

// ---- split-K reduce: out = sum of 8 partial tiles ----
__global__ void kan_reduce(const float* __restrict__ part, float* __restrict__ out) {
  const size_t j = ((size_t)blockIdx.x * 256 + threadIdx.x) * 4;
  float4 a = *(const float4*)(part + j);
  #pragma unroll
  for (int s = 1; s < 8; s++) {
    float4 b = *(const float4*)(part + (size_t)s * 1048576 + j);
    a.x += b.x; a.y += b.y; a.z += b.z; a.w += b.w;
  }
  *(float4*)(out + j) = a;
}

// ---- naive fallback (only if d_ws is too small): correct, slow ----
__global__ void kan_naive(const float* __restrict__ x, const float* __restrict__ bw,
                          const float* __restrict__ sw, const float* __restrict__ sca,
                          float* __restrict__ out) {
  const int o = threadIdx.x;
  const int b = blockIdx.x;
  float accb = 0.0f, accs = 0.0f, scl = 0.0f;
  for (int i = 0; i < IN_F; i++) {
    const float xraw = x[(size_t)b * IN_F + i];
    accb += xraw * bw[(size_t)i * OUT_F + o];
    scl += fmaxf(sca[(size_t)i * OUT_F + o], 1e-7f);
    const float xc = fminf(fmaxf(xraw, -1.0f), 1.0f);
    const float xs = (xc + 1.0f) * (63.0f / (2.0f + 1e-7f));
    const float tl = xs - fminf(floorf(xs), 61.0f);
    const int kc = (int)(tl * 65.0f + 0.5f);
    const int k0 = max(0, min(kc - 8, 50));
    float e[16]; float s = 0.0f;
    #pragma unroll
    for (int j = 0; j < 16; j++) {
      float d = tl - (float)(k0 + j) * (1.0f / 65.0f);
      e[j] = __expf(-2178.0f * d * d);
      s += e[j];
    }
    const float r = __fdividef(1.0f, s + 1e-7f);
    const float* wrow = sw + ((size_t)i * OUT_F + o) * NB + k0;
    float dot = 0.0f;
    #pragma unroll
    for (int j = 0; j < 16; j++) dot += e[j] * wrow[j];
    accs += dot * r;
  }
  out[(size_t)b * OUT_F + o] = accb + accs * (scl * (1.0f / 256.0f));
}

extern "C" void kernel_launch(void* const* d_in, const int* in_sizes, int n_in,
                              void* d_out, int out_size, void* d_ws, size_t ws_size,
                              hipStream_t stream) {
  const float* x   = (const float*)d_in[0];
  const float* bw  = (const float*)d_in[1];
  const float* sw  = (const float*)d_in[2];
  const float* sca = (const float*)d_in[3];
  float* out = (float*)d_out;

  const size_t WP2_BYTES  = (size_t)IN_F * OUT_F * KP * 2;          // 10485760
  const size_t WP_OFF     = 8192;                                   // after wsp[8][256]
  const size_t PART_OFF   = WP_OFF + WP2_BYTES;                     // 10493952
  const size_t PART_BYTES = (size_t)KSPLIT * 4096 * OUT_F * 4;      // 33554432

  if (ws_size >= PART_OFF + PART_BYTES) {
    float* wsp = (float*)d_ws;
    unsigned short* wp2 = (unsigned short*)((char*)d_ws + WP_OFF);
    float* part = (float*)((char*)d_ws + PART_OFF);
    kan_scale8<<<8, 256, 0, stream>>>(sca, wsp);
    kan_pack<<<256, 256, 0, stream>>>(sw, bw, wsp, wp2);
    kan_main<<<256, NTHREADS, 0, stream>>>(x, wp2, part, 0);
    kan_reduce<<<1024, 256, 0, stream>>>(part, out);
  } else if (ws_size >= PART_OFF) {
    float* wsp = (float*)d_ws;
    unsigned short* wp2 = (unsigned short*)((char*)d_ws + WP_OFF);
    hipMemsetAsync(d_out, 0, (size_t)out_size * sizeof(float), stream);
    kan_scale8<<<8, 256, 0, stream>>>(sca, wsp);
    kan_pack<<<256, 256, 0, stream>>>(sw, bw, wsp, wp2);
    kan_main<<<256, NTHREADS, 0, stream>>>(x, wp2, out, 1);
  } else {
    kan_naive<<<4096, 256, 0, stream>>>(x, bw, sw, sca, out);
  }
}

// Round 4
// 211.944 us; speedup vs baseline: 1.0112x; 1.0112x over previous
//
#include <hip/hip_runtime.h>
#include <stdint.h>

// KANLinear fused kernel v4 for MI355X (gfx950).
// out = x @ bw + scaling * einsum('bik,iok->bo', basis(x), sw)
// One bf16 MFMA GEMM: K = 256 i-slabs x 80 (66 basis + base term at k=66 + zero pad).
// v4 vs v3 (which SPILLED: VGPR 60 < 64-acc, WRITE 357MB scratch, main 136us):
//   - __launch_bounds__(512,1): no forced reg cap -> no spill (expect ~190 regs)
//   - 64x64 wave tile (10 ds_read_b128/wave/slab), 2 slabs per barrier (16 stages),
//     A dbuf 2x2x128x88 = 90KB LDS; basis wave-split: waves 0-3 slab-even, 4-7 slab-odd
//   - B double-buffered in regs per half-stage (breg[2][10]), loads ~1300cyc ahead
//   - XOR sub-chunk swizzle on A LDS (breaks APAD=88's 4-way conflict to free 2-way)
//   - reduce fused into main epilogue (last-arriver per m-tile, threadfence+atomic cnt)
//   - pack: single-barrier LDS transpose, 512 thr/block, conflict-free (67-stride)

#define IN_F 256
#define OUT_F 256
#define NB 66
#define KP 80        // padded K per i-slab: 66 basis + base at k=66 + zeros, = 5 x K16
#define APAD 88      // A LDS row stride in ushorts (16B-aligned rows)
#define KSPLIT 8
#define SLABS 32     // IN_F / KSPLIT
#define STAGES 16    // 2 slabs per stage
#define BM 128
#define NTHREADS 512

typedef __attribute__((ext_vector_type(8))) short bf16x8;
typedef __attribute__((ext_vector_type(16))) float f32x16;

__device__ __forceinline__ unsigned int f2bf(float f) {
  unsigned int u = __float_as_uint(f);
  u += 0x7FFFu + ((u >> 16) & 1u);   // round-to-nearest-even
  return u >> 16;
}

// ---- scaling partial: block b sums i in [b*32, b*32+32) ----
__global__ void kan_scale8(const float* __restrict__ sca, float* __restrict__ wsp) {
  const int o = threadIdx.x, b = blockIdx.x;
  float s = 0.0f;
  #pragma unroll
  for (int j = 0; j < 32; j++) {
    const int i = b * 32 + j;
    s += fmaxf(sca[(size_t)i * OUT_F + o], 1e-7f);
  }
  wsp[b * OUT_F + o] = s;
}

// ---- pack W' -> wp2, layout (i*10 + g)*256 + o as uint4 (8 bf16), chunk k = g*8+j ----
// k<66 = sw*scaling[o]; k=66 = bw; 67..79 = 0. One-barrier LDS transpose, coalesced.
__global__ __launch_bounds__(512) void kan_pack(const float* __restrict__ sw,
                                                const float* __restrict__ bw,
                                                const float* __restrict__ wsp,
                                                unsigned short* __restrict__ wp2) {
  __shared__ float S[256 * 67 + 16];
  const int t = threadIdx.x, i = blockIdx.x;
  const float* src = sw + (size_t)i * (256 * 66);
  #pragma unroll
  for (int r2 = 0; r2 < 33; r2++) {           // 16896 = 33*512 contiguous floats
    const int idx = r2 * 512 + t;
    const int o = idx / 66;
    const int k = idx - o * 66;
    S[o * 67 + k] = src[idx];
  }
  __syncthreads();
  const int og = t >> 1, hh = t & 1;
  float scv = 0.0f;
  #pragma unroll
  for (int b = 0; b < 8; b++) scv += wsp[b * 256 + og];
  scv *= (1.0f / 256.0f);
  const float bwv = bw[(size_t)i * 256 + og];
  const float* Sr = S + og * 67;
  uint4* wp2u4 = (uint4*)wp2;
  #pragma unroll
  for (int gg = 0; gg < 5; gg++) {
    const int g = hh * 5 + gg;
    const int kb = g * 8;
    unsigned int u[4];
    #pragma unroll
    for (int j = 0; j < 4; j++) {
      const int k0 = kb + 2 * j, k1 = k0 + 1;
      float f0 = (k0 < 66) ? Sr[k0] * scv : ((k0 == 66) ? bwv : 0.0f);
      float f1 = (k1 < 66) ? Sr[k1] * scv : ((k1 == 66) ? bwv : 0.0f);
      u[j] = f2bf(f0) | (f2bf(f1) << 16);
    }
    uint4 v; v.x = u[0]; v.y = u[1]; v.z = u[2]; v.w = u[3];
    wp2u4[((size_t)i * 10 + g) * 256 + og] = v;
  }
}

// ---- main fused GEMM ----
__global__ __launch_bounds__(NTHREADS, 1) void kan_main(
    const float* __restrict__ x, const unsigned short* __restrict__ wp2,
    float* __restrict__ part, float* __restrict__ outp,
    int* __restrict__ cnt, int atomic_mode) {
  __shared__ unsigned short A[2][2 * BM * APAD];   // 90112 B: stage-dbuf x 2 sub-slabs
  __shared__ int lastflag;

  const int t = threadIdx.x;
  const int lane = t & 63;
  const int w = t >> 6;            // 0..7
  const int ml = lane & 31;
  const int half = lane >> 5;
  const int mr = w >> 2;           // wave M-row 0..1 (64 rows each)
  const int nc = w & 3;            // wave N-col 0..3 (64 cols each)
  const int mblk = (int)blockIdx.x >> 3;
  const int kidx = (int)blockIdx.x & 7;   // XCD-affine split-K index
  const int b0 = mblk * BM;
  const int ibase = kidx * SLABS;

  // basis mapping: waves 0-3 stage sub-slab 0, waves 4-7 sub-slab 1 (wave-uniform)
  const int sl = t >> 8;
  const int rb = (t & 255) >> 1;   // row 0..127
  const int hh = t & 1;

  const float* xrow = x + (size_t)(b0 + rb) * IN_F;
  const unsigned short* bbase = wp2 + half * 2048 + (nc * 64 + ml) * 8;

  bf16x8 breg[2][10];
  f32x16 acc[4] = {f32x16{}, f32x16{}, f32x16{}, f32x16{}};

#define LOADB(P, ISLAB)                                                        \
  {                                                                            \
    const unsigned short* bp = bbase + (size_t)(ISLAB) * (OUT_F * KP);         \
    _Pragma("unroll") for (int kk = 0; kk < 5; kk++) {                         \
      breg[P][2 * kk] = *(const bf16x8*)(bp + kk * 4096);                      \
      breg[P][2 * kk + 1] = *(const bf16x8*)(bp + kk * 4096 + 256);            \
    }                                                                          \
  }

  // stage basis: thread fills row rb of sub-slab sl in A[BUF] with basis(XV)
#define STAGE2(BUF, XV)                                                        \
  {                                                                            \
    const float xr_ = (XV);                                                    \
    const float xc_ = fminf(fmaxf(xr_, -1.0f), 1.0f);                          \
    const float xs_ = (xc_ + 1.0f) * (63.0f / (2.0f + 1e-7f));                 \
    const float tl_ = xs_ - fminf(floorf(xs_), 61.0f);                         \
    const int kc_ = (int)(tl_ * 65.0f + 0.5f);                                 \
    const int c0_ = (min(max(kc_ - 8, 0), 50)) >> 4;                           \
    unsigned short* Ar = &A[BUF][sl * BM * APAD + rb * APAD];                  \
    const int rbit_ = (rb >> 3) & 1;                                           \
    const int kb = (c0_ + hh) * 16;                                            \
    float vv[16];                                                              \
    float s_ = 0.0f;                                                           \
    _Pragma("unroll") for (int j = 0; j < 16; j++) {                           \
      const float d_ = tl_ - (float)(kb + j) * (1.0f / 65.0f);                 \
      float ee = __expf(-2178.0f * d_ * d_);                                   \
      ee = (kb + j < 66) ? ee : 0.0f;                                          \
      vv[j] = ee;                                                              \
      s_ += ee;                                                                \
    }                                                                          \
    s_ += __shfl_xor(s_, 1);                                                   \
    const float r_ = __fdividef(1.0f, s_ + 1e-7f);                             \
    unsigned int u[8];                                                         \
    _Pragma("unroll") for (int j = 0; j < 8; j++) {                            \
      float f0 = vv[2 * j] * r_;                                               \
      float f1 = vv[2 * j + 1] * r_;                                           \
      f0 = (kb + 2 * j == 66) ? xr_ : f0;                                      \
      f1 = (kb + 2 * j + 1 == 66) ? xr_ : f1;                                  \
      u[j] = f2bf(f0) | (f2bf(f1) << 16);                                      \
    }                                                                          \
    uint4 v0, v1;                                                              \
    v0.x = u[0]; v0.y = u[1]; v0.z = u[2]; v0.w = u[3];                        \
    v1.x = u[4]; v1.y = u[5]; v1.z = u[6]; v1.w = u[7];                        \
    *(uint4*)(Ar + ((((kb >> 3) + 0) ^ rbit_) << 3)) = v0;                     \
    *(uint4*)(Ar + ((((kb >> 3) + 1) ^ rbit_) << 3)) = v1;                     \
    uint4 z; z.x = 0; z.y = 0; z.z = 0; z.w = 0;                               \
    if (hh == 0) {                                                             \
      const int f0_ = (c0_ == 0) ? 2 : 0;                                      \
      const int f1_ = (c0_ <= 1) ? 3 : 1;                                      \
      *(uint4*)(Ar + (((f0_ * 2 + 0) ^ rbit_) << 3)) = z;                      \
      *(uint4*)(Ar + (((f0_ * 2 + 1) ^ rbit_) << 3)) = z;                      \
      *(uint4*)(Ar + (((f1_ * 2 + 0) ^ rbit_) << 3)) = z;                      \
      *(uint4*)(Ar + (((f1_ * 2 + 1) ^ rbit_) << 3)) = z;                      \
    } else {                                                                   \
      const int f2_ = (c0_ == 3) ? 2 : 4;                                      \
      uint4 a = z;                                                             \
      a.y = (f2_ == 4) ? f2bf(xr_) : 0u;  /* x at k=66: chunk4 dword1 low */   \
      *(uint4*)(Ar + (((f2_ * 2 + 0) ^ rbit_) << 3)) = a;                      \
      *(uint4*)(Ar + (((f2_ * 2 + 1) ^ rbit_) << 3)) = z;                      \
    }                                                                          \
  }

#define MFMA_SLAB(CUR, SSEL, P)                                                \
  {                                                                            \
    const unsigned short* As = &A[CUR][(SSEL) * BM * APAD];                    \
    const int rbit_ = (ml >> 3) & 1;                                           \
    _Pragma("unroll") for (int kk = 0; kk < 5; kk++) {                         \
      const int so_ = ((kk * 2 + half) ^ rbit_) << 3;                          \
      bf16x8 a0 = *(const bf16x8*)(As + (mr * 64 + ml) * APAD + so_);          \
      bf16x8 a1 = *(const bf16x8*)(As + (mr * 64 + 32 + ml) * APAD + so_);     \
      acc[0] = __builtin_amdgcn_mfma_f32_32x32x16_bf16(a0, breg[P][2 * kk], acc[0], 0, 0, 0);     \
      acc[1] = __builtin_amdgcn_mfma_f32_32x32x16_bf16(a0, breg[P][2 * kk + 1], acc[1], 0, 0, 0); \
      acc[2] = __builtin_amdgcn_mfma_f32_32x32x16_bf16(a1, breg[P][2 * kk], acc[2], 0, 0, 0);     \
      acc[3] = __builtin_amdgcn_mfma_f32_32x32x16_bf16(a1, breg[P][2 * kk + 1], acc[3], 0, 0, 0); \
    }                                                                          \
  }

  // ---- prologue: stage 0 basis + B(sub0) ----
  STAGE2(0, xrow[ibase + sl]);
  LOADB(0, ibase);
  float xn = xrow[ibase + 2 + sl];   // x for stage 1 (SLABS>2 always)
  __syncthreads();

  for (int st = 0; st < STAGES; st++) {
    const int cur = st & 1;
    const int s0 = ibase + st * 2;
    LOADB(1, s0 + 1);                          // B sub1, consumed this stage
    MFMA_SLAB(cur, 0, 0);
    if (st + 1 < STAGES) LOADB(0, s0 + 2);     // B sub0 next stage
    MFMA_SLAB(cur, 1, 1);
    const float xc2 = xn;
    if (st + 2 < STAGES) xn = xrow[ibase + (st + 2) * 2 + sl];
    if (st + 1 < STAGES) STAGE2(1 - cur, xc2);
    __syncthreads();
  }

  // ---- epilogue: C/D layout col=lane&31, row=(r&3)+8*(r>>2)+4*(lane>>5) ----
  const int colb = nc * 64 + ml;
  if (atomic_mode) {
    #pragma unroll
    for (int r = 0; r < 16; r++) {
      const int row0 = b0 + mr * 64 + (r & 3) + 8 * (r >> 2) + 4 * half;
      atomicAdd(&part[(size_t)row0 * OUT_F + colb], acc[0][r]);
      atomicAdd(&part[(size_t)row0 * OUT_F + colb + 32], acc[1][r]);
      atomicAdd(&part[(size_t)(row0 + 32) * OUT_F + colb], acc[2][r]);
      atomicAdd(&part[(size_t)(row0 + 32) * OUT_F + colb + 32], acc[3][r]);
    }
    return;
  }
  float* pd = part + (size_t)kidx * ((size_t)4096 * OUT_F);
  #pragma unroll
  for (int r = 0; r < 16; r++) {
    const int row0 = b0 + mr * 64 + (r & 3) + 8 * (r >> 2) + 4 * half;
    pd[(size_t)row0 * OUT_F + colb] = acc[0][r];
    pd[(size_t)row0 * OUT_F + colb + 32] = acc[1][r];
    pd[(size_t)(row0 + 32) * OUT_F + colb] = acc[2][r];
    pd[(size_t)(row0 + 32) * OUT_F + colb + 32] = acc[3][r];
  }

  // ---- fused split-K reduce: last-arriving block per m-tile sums the 8 partials ----
  __threadfence();                         // release our partial writes (device scope)
  if (t == 0) lastflag = (atomicAdd(&cnt[mblk], 1) == KSPLIT - 1);
  __syncthreads();
  if (lastflag) {
    __threadfence();                       // acquire: other blocks' writes now visible
    const float4* pp = (const float4*)(part + (size_t)b0 * OUT_F);
    float4* po = (float4*)(outp + (size_t)b0 * OUT_F);
    #pragma unroll
    for (int j = 0; j < 16; j++) {         // 128*256/4 = 8192 float4 / 512 thr
      const int vi = j * 512 + t;
      float4 a = pp[vi];
      #pragma unroll
      for (int s2 = 1; s2 < 8; s2++) {
        float4 b4 = pp[(size_t)s2 * 262144 + vi];   // 4096*256/4 per split
        a.x += b4.x; a.y += b4.y; a.z += b4.z; a.w += b4.w;
      }
      po[vi] = a;
    }
  }
}

// ---- naive fallback (only if d_ws is too small): correct, slow ----
__global__ void kan_naive(const float* __restrict__ x, const float* __restrict__ bw,
                          const float* __restrict__ sw, const float* __restrict__ sca,
                          float* __restrict__ out) {
  const int o = threadIdx.x;
  const int b = blockIdx.x;
  float accb = 0.0f, accs = 0.0f, scl = 0.0f;
  for (int i = 0; i < IN_F; i++) {
    const float xraw = x[(size_t)b * IN_F + i];
    accb += xraw * bw[(size_t)i * OUT_F + o];
    scl += fmaxf(sca[(size_t)i * OUT_F + o], 1e-7f);
    const float xc = fminf(fmaxf(xraw, -1.0f), 1.0f);
    const float xs = (xc + 1.0f) * (63.0f / (2.0f + 1e-7f));
    const float tl = xs - fminf(floorf(xs), 61.0f);
    const int kc = (int)(tl * 65.0f + 0.5f);
    const int k0 = max(0, min(kc - 8, 50));
    float e[16]; float s = 0.0f;
    #pragma unroll
    for (int j = 0; j < 16; j++) {
      float d = tl - (float)(k0 + j) * (1.0f / 65.0f);
      e[j] = __expf(-2178.0f * d * d);
      s += e[j];
    }
    const float r = __fdividef(1.0f, s + 1e-7f);
    const float* wrow = sw + ((size_t)i * OUT_F + o) * NB + k0;
    float dot = 0.0f;
    #pragma unroll
    for (int j = 0; j < 16; j++) dot += e[j] * wrow[j];
    accs += dot * r;
  }
  out[(size_t)b * OUT_F + o] = accb + accs * (scl * (1.0f / 256.0f));
}

extern "C" void kernel_launch(void* const* d_in, const int* in_sizes, int n_in,
                              void* d_out, int out_size, void* d_ws, size_t ws_size,
                              hipStream_t stream) {
  const float* x   = (const float*)d_in[0];
  const float* bw  = (const float*)d_in[1];
  const float* sw  = (const float*)d_in[2];
  const float* sca = (const float*)d_in[3];
  float* out = (float*)d_out;

  const size_t CNT_OFF    = 8192;                                   // 32 ints
  const size_t WP_OFF     = 16384;
  const size_t WP2_BYTES  = (size_t)IN_F * OUT_F * KP * 2;          // 10485760
  const size_t PART_OFF   = WP_OFF + WP2_BYTES;                     // 10502144
  const size_t PART_BYTES = (size_t)KSPLIT * 4096 * OUT_F * 4;      // 33554432

  if (ws_size >= PART_OFF + PART_BYTES) {
    float* wsp = (float*)d_ws;
    int* cnt = (int*)((char*)d_ws + CNT_OFF);
    unsigned short* wp2 = (unsigned short*)((char*)d_ws + WP_OFF);
    float* part = (float*)((char*)d_ws + PART_OFF);
    hipMemsetAsync(cnt, 0, 128, stream);
    kan_scale8<<<8, 256, 0, stream>>>(sca, wsp);
    kan_pack<<<256, 512, 0, stream>>>(sw, bw, wsp, wp2);
    kan_main<<<256, NTHREADS, 0, stream>>>(x, wp2, part, out, cnt, 0);
  } else if (ws_size >= PART_OFF) {
    float* wsp = (float*)d_ws;
    unsigned short* wp2 = (unsigned short*)((char*)d_ws + WP_OFF);
    hipMemsetAsync(d_out, 0, (size_t)out_size * sizeof(float), stream);
    kan_scale8<<<8, 256, 0, stream>>>(sca, wsp);
    kan_pack<<<256, 512, 0, stream>>>(sw, bw, wsp, wp2);
    kan_main<<<256, NTHREADS, 0, stream>>>(x, wp2, out, nullptr, nullptr, 1);
  } else {
    kan_naive<<<4096, 256, 0, stream>>>(x, bw, sw, sca, out);
  }
}